// Round 8
// baseline (417.221 us; speedup 1.0000x reference)
//
#include <hip/hip_runtime.h>

typedef unsigned short u16;
typedef unsigned int u32;

typedef __attribute__((ext_vector_type(8))) __bf16 bf16x8;
typedef __attribute__((ext_vector_type(4))) float floatx4;

#define B_ 2
#define L_ 2048
#define H_ 16
#define E_ 64
#define QK_ELEMS (B_ * L_ * H_ * E_) /* 4194304 elems; bf16 = 8 MB */

static __device__ __forceinline__ u32 pk2bf(float a, float b) {
  u32 ua = __builtin_bit_cast(u32, a), ub = __builtin_bit_cast(u32, b);
  return ((ua + 0x8000u) >> 16) | (((ub + 0x8000u) >> 16) << 16);
}
static __device__ __forceinline__ u16 f2bf1(float a) {
  return (u16)((__builtin_bit_cast(u32, a) + 0x8000u) >> 16);
}

// RoPE 4 pairs in fp32: pair m uses freq idx pbase+m, theta=10000^(-j/16).
// v_sin/v_cos take revolutions; fract keeps arg in range (err ~2e-4 rad @ l=2047).
static __device__ __forceinline__ void rope_pairs(float* x, float pos, int pbase) {
  const float LB = 0.83048202372184058696f;   // log2(10000)/16
  const float I2P = 0.15915494309189533577f;  // 1/(2*pi)
#pragma unroll
  for (int m = 0; m < 4; ++m) {
    float fr = exp2f(-(float)(pbase + m) * LB) * I2P;
    float a = pos * fr;
    a -= floorf(a);
    float s = __builtin_amdgcn_sinf(a);
    float c = __builtin_amdgcn_cosf(a);
    float e0 = x[2 * m], e1 = x[2 * m + 1];
    x[2 * m] = c * e0 - s * e1;
    x[2 * m + 1] = c * e1 + s * e0;
  }
}

// ---------- fused prepass (verified R5/R6) ----------
// blocks [0,2048): RoPE K fp32->bf16, relayout (B,L,H,E)->(B,H,L,E)
// blocks [2048,3072): V fp32 (B,L,H,E) -> VT' bf16 (B,H,E,L) with the PV key
// permutation sigma baked in per 32-key block: VT'[.., k0+p] = V[k0+sigma(p)],
// sigma(p) = (p>>3)*4 + (p&3) + ((p>>2)&1)*16.  (Makes flash's P A-fragment
// equal the lane's own QK^T C-registers -> no LDS round-trip in the hot loop.)
__global__ __launch_bounds__(256) void prep(const float* __restrict__ K,
                                            const float* __restrict__ V,
                                            u16* __restrict__ Kr,
                                            u16* __restrict__ VT) {
  __shared__ u16 tile[64][65];
  int t = threadIdx.x;
  if (blockIdx.x < 2048) {
    int R = blockIdx.x * 32 + (t >> 3);     // row id in (b,l,h) order
    int chunk = t & 7, e0 = chunk << 3;
    int b = R >> 15, l = (R >> 4) & (L_ - 1), h = R & 15;
    const float* src = K + ((size_t)R << 6) + e0;
    float4 A = *(const float4*)src, Bv = *(const float4*)(src + 4);
    float x[8] = {A.x, A.y, A.z, A.w, Bv.x, Bv.y, Bv.z, Bv.w};
    if (chunk < 4) rope_pairs(x, (float)l, chunk * 4);  // dims < 32 rotate
    uint4 o;
    o.x = pk2bf(x[0], x[1]); o.y = pk2bf(x[2], x[3]);
    o.z = pk2bf(x[4], x[5]); o.w = pk2bf(x[6], x[7]);
    *(uint4*)(Kr + (((size_t)(b * H_ + h) * L_ + l) << 6) + e0) = o;
  } else {
    int blk = blockIdx.x - 2048;      // 32 bh * 32 ltiles
    int bh = blk & 31, lt = blk >> 5;
    int b = bh >> 4, h = bh & 15;
    int l0 = lt << 6;
#pragma unroll
    for (int it = 0; it < 2; ++it) {
      int ll = (t >> 3) + (it << 5);
      int dc = (t & 7) << 3;
      const float* src = V + (((size_t)(b * L_ + l0 + ll) * H_ + h) << 6) + dc;
      float4 A = *(const float4*)src, Bv = *(const float4*)(src + 4);
      tile[ll][dc + 0] = f2bf1(A.x); tile[ll][dc + 1] = f2bf1(A.y);
      tile[ll][dc + 2] = f2bf1(A.z); tile[ll][dc + 3] = f2bf1(A.w);
      tile[ll][dc + 4] = f2bf1(Bv.x); tile[ll][dc + 5] = f2bf1(Bv.y);
      tile[ll][dc + 6] = f2bf1(Bv.z); tile[ll][dc + 7] = f2bf1(Bv.w);
    }
    __syncthreads();
    int e = t >> 2, lg = (t & 3) << 4;     // keys lg..lg+15 (within one 32-block)
    u32 pk[8];
#pragma unroll
    for (int i = 0; i < 8; ++i)
      pk[i] = (u32)tile[lg + 2 * i][e] | ((u32)tile[lg + 2 * i + 1][e] << 16);
    // sigma-permuted store: key m (0..15 rel. to lg) -> pos p=(m>>2)*8+ch*4+(m&3)
    int ch = (lg >> 4) & 1;
    u32* dst = (u32*)VT + ((size_t)bh * E_ + e) * (L_ / 2) + ((l0 + (lg & 32)) >> 1) + 2 * ch;
    *(uint2*)(dst + 0)  = make_uint2(pk[0], pk[1]);
    *(uint2*)(dst + 4)  = make_uint2(pk[2], pk[3]);
    *(uint2*)(dst + 8)  = make_uint2(pk[4], pk[5]);   // R7 bug was pk[7-3]==pk[4]
    *(uint2*)(dst + 12) = make_uint2(pk[6], pk[7]);
  }
}

// ---------- main flash kernel ----------
// Block = one rowblk (32 q-rows) of one (b,h); 4 waves split the key range 4-way
// (static-max softmax => partials are pure sums). Partial O/l reduced through an
// 8 KB LDS buffer (sequential wave-accumulate), then ONE coalesced non-atomic
// store with the 1/l normalization fused. No atomics, no memsets, no normalize.
// mfma_f32_16x16x32_bf16 lane maps (m89/m120-verified):
//   A[m=lane&15][k=quad*8+j]  B[k=quad*8+j][n=lane&15]  C/D: col=lane&15, row=quad*4+reg
// S^T = MFMA(A=K, B=Q): lane holds S[s=ch*16+quad*4+r][q=rh*16+l16].
// PV with sigma-permuted keys (VT' prepass): P A-frag = lane's OWN packed regs.
__global__ __launch_bounds__(256, 4) void flash(
    const float* __restrict__ Q, const u16* __restrict__ Kr,
    const u16* __restrict__ VT, const float* __restrict__ bw,
    float* __restrict__ out) {
  __shared__ float obuf[32][65];   // padded: +1 breaks the 64-stride bank alias
  __shared__ float lbufs[32];
  const int tid = threadIdx.x;
  const int wid = tid >> 6, lane = tid & 63;
  const int quad = lane >> 4, l16 = lane & 15;
  const int bh = blockIdx.x & 31;       // low 5 bits -> XCD round-robin L2 locality
  const int rowblk = blockIdx.x >> 5;   // 0..63
  const int row0 = rowblk << 5;
  const int var_l = rowblk >> 1;
  const int nst = 1 + (rowblk & 1);     // t0=0: kt=0 only; t0=32: kt=0,1
  const int b = bh >> 4, h = bh & 15;
  const int vbase = wid << 3;           // each wave: 8 vars

  const u16* Kb = Kr + ((size_t)bh << 17);
  const u16* Vb = VT + ((size_t)bh << 17);

  const float L2E = 1.4426950408889634f;
  const float SCL2 = 0.125f * L2E;
  const float bd = bw[h] * L2E, bs = bw[H_ + h] * L2E;

  const floatx4 zero4 = {0.f, 0.f, 0.f, 0.f};
  bf16x8 ones;
  { uint4 t4; t4.x = t4.y = t4.z = t4.w = 0x3F803F80u; ones = __builtin_bit_cast(bf16x8, t4); }

  // Q B-frags (n=l16 = q-row), RoPE fused once per wave
  bf16x8 qf[2][2];
#pragma unroll
  for (int rh = 0; rh < 2; ++rh) {
    const int row = row0 + rh * 16 + l16;
    const float* qrow = Q + (((size_t)(b * L_ + row)) * H_ + h) * E_;
#pragma unroll
    for (int hf = 0; hf < 2; ++hf) {
      const float* p = qrow + hf * 32 + quad * 8;
      float4 A = *(const float4*)p, Bv = *(const float4*)(p + 4);
      float x[8] = {A.x, A.y, A.z, A.w, Bv.x, Bv.y, Bv.z, Bv.w};
      if (hf == 0) rope_pairs(x, (float)row, quad * 4);
      uint4 o;
      o.x = pk2bf(x[0], x[1]); o.y = pk2bf(x[2], x[3]);
      o.z = pk2bf(x[4], x[5]); o.w = pk2bf(x[6], x[7]);
      qf[rh][hf] = __builtin_bit_cast(bf16x8, o);
    }
  }

  // mask: key s = ch*16+quad*4+r masked iff r > mth[ch][rh] (t0 cancels)
  int mth[2][2];
#pragma unroll
  for (int ch = 0; ch < 2; ++ch)
#pragma unroll
    for (int rh = 0; rh < 2; ++rh)
      mth[ch][rh] = rh * 16 + l16 - ch * 16 - quad * 4;

  floatx4 oacc[2][4], lacc[2];
#pragma unroll
  for (int rh = 0; rh < 2; ++rh) {
    lacc[rh] = zero4;
#pragma unroll
    for (int c4 = 0; c4 < 4; ++c4) oacc[rh][c4] = zero4;
  }

  auto run = [&](int nst_c) {
#pragma unroll
    for (int vi = 0; vi < 8; ++vi) {
      const int v = vbase + vi;
      const float bias2 = (v == var_l) ? bs : bd;
#pragma unroll
      for (int kt = 0; kt < nst_c; ++kt) {
        const bool dm = (kt == nst_c - 1);
        const int k0 = (v << 6) + (kt << 5);

        bf16x8 kf[2][2], vf[4];
#pragma unroll
        for (int ch = 0; ch < 2; ++ch)
#pragma unroll
          for (int hf = 0; hf < 2; ++hf)
            kf[ch][hf] = *(const bf16x8*)(Kb + ((k0 + ch * 16 + l16) << 6) + hf * 32 + quad * 8);
#pragma unroll
        for (int c4 = 0; c4 < 4; ++c4)
          vf[c4] = *(const bf16x8*)(Vb + ((c4 * 16 + l16) << 11) + k0 + quad * 8);

        floatx4 cc[2][2];
#pragma unroll
        for (int ch = 0; ch < 2; ++ch)
#pragma unroll
          for (int rh = 0; rh < 2; ++rh) {
            floatx4 acc = __builtin_amdgcn_mfma_f32_16x16x32_bf16(kf[ch][0], qf[rh][0], zero4, 0, 0, 0);
            cc[ch][rh] = __builtin_amdgcn_mfma_f32_16x16x32_bf16(kf[ch][1], qf[rh][1], acc, 0, 0, 0);
          }

        u32 pk01[2][2], pk23[2][2];
#pragma unroll
        for (int ch = 0; ch < 2; ++ch)
#pragma unroll
          for (int rh = 0; rh < 2; ++rh) {
            const floatx4 c = cc[ch][rh];
            float pv[4];
#pragma unroll
            for (int r = 0; r < 4; ++r) {
              float arg = c[r] * SCL2 + bias2;
              if (dm && (r > mth[ch][rh])) arg = -1e30f;
              pv[r] = exp2f(arg);
            }
            pk01[ch][rh] = pk2bf(pv[0], pv[1]);
            pk23[ch][rh] = pk2bf(pv[2], pv[3]);
          }

#pragma unroll
        for (int rh = 0; rh < 2; ++rh) {
          uint4 paw;
          paw.x = pk01[0][rh]; paw.y = pk23[0][rh];
          paw.z = pk01[1][rh]; paw.w = pk23[1][rh];
          bf16x8 pa = __builtin_bit_cast(bf16x8, paw);
          lacc[rh] = __builtin_amdgcn_mfma_f32_16x16x32_bf16(pa, ones, lacc[rh], 0, 0, 0);
#pragma unroll
          for (int c4 = 0; c4 < 4; ++c4)
            oacc[rh][c4] = __builtin_amdgcn_mfma_f32_16x16x32_bf16(pa, vf[c4], oacc[rh][c4], 0, 0, 0);
        }
      }
    }
  };
  if (nst == 2) run(2); else run(1);

  // ---- block reduction of O/l partials through LDS (no atomics) ----
#pragma unroll 1
  for (int w = 0; w < 4; ++w) {
    if (wid == w) {
#pragma unroll
      for (int rh = 0; rh < 2; ++rh)
#pragma unroll
        for (int r = 0; r < 4; ++r) {
          const int row = rh * 16 + quad * 4 + r;
#pragma unroll
          for (int c4 = 0; c4 < 4; ++c4) {
            const int col = c4 * 16 + l16;
            if (w == 0) obuf[row][col] = oacc[rh][c4][r];
            else obuf[row][col] += oacc[rh][c4][r];
          }
          if (l16 == 0) {
            if (w == 0) lbufs[row] = lacc[rh][r];
            else lbufs[row] += lacc[rh][r];
          }
        }
    }
    __syncthreads();
  }

  // ---- fused normalize + coalesced store ----
  {
    const int row = tid >> 3, cb = (tid & 7) << 3;
    const float rv = 1.0f / lbufs[row];
    float* dst = out + (((size_t)(b * L_ + row0 + row)) * H_ + h) * E_ + cb;
    float4 x0, x1;
    x0.x = obuf[row][cb + 0] * rv; x0.y = obuf[row][cb + 1] * rv;
    x0.z = obuf[row][cb + 2] * rv; x0.w = obuf[row][cb + 3] * rv;
    x1.x = obuf[row][cb + 4] * rv; x1.y = obuf[row][cb + 5] * rv;
    x1.z = obuf[row][cb + 6] * rv; x1.w = obuf[row][cb + 7] * rv;
    *(float4*)dst = x0;
    *(float4*)(dst + 4) = x1;
  }
}

extern "C" void kernel_launch(void* const* d_in, const int* in_sizes, int n_in,
                              void* d_out, int out_size, void* d_ws, size_t ws_size,
                              hipStream_t stream) {
  (void)in_sizes; (void)n_in; (void)out_size; (void)ws_size;
  const float* q = (const float*)d_in[0];
  const float* k = (const float*)d_in[1];
  const float* v = (const float*)d_in[2];
  const float* bwp = (const float*)d_in[3];
  // d_in[4]=n_vars(=32), d_in[5]=n_tokens(=64): fixed by setup, hardcoded.
  float* out = (float*)d_out;
  u16* Kr = (u16*)d_ws;                                  // 8 MB
  u16* VT = Kr + QK_ELEMS;                               // 8 MB
  prep<<<3072, 256, 0, stream>>>(k, v, Kr, VT);
  flash<<<2048, 256, 0, stream>>>(q, Kr, VT, bwp, out);
}